// Round 1
// baseline (1533.054 us; speedup 1.0000x reference)
//
#include <hip/hip_runtime.h>
#include <hip/hip_bf16.h>

// MoE forward, B=4096 E=8 D=1024 H=4096 O=1024, fp32 in/out, bf16 MFMA compute.
//
// out = sum_e p[b,e] * (relu(x @ W1[e] + b1[e]) @ W2[e] + b2[e])
//     = (h' @ W2flat) + sum_e p[b,e]*b2[e]      with h'[b, e*H+h] = p[b,e]*relu(...)
//
// Stage A: gating probs (fp32), x->bf16, W1 -> W1t [E*H][D] bf16, W2 -> W2t [O][E*H] bf16
// Stage B: GEMM1 (M=4096,N=32768,K=1024) epilogue relu*p -> h' bf16
// Stage C: GEMM2 (M=4096,N=1024,K=32768) epilogue + sum_e p*b2 -> out fp32

#define B_DIM 4096
#define E_DIM 8
#define D_DIM 1024
#define H_DIM 4096
#define O_DIM 1024
#define KTOT  (E_DIM * H_DIM)   // 32768

typedef __attribute__((ext_vector_type(8))) short bf16x8;
typedef __attribute__((ext_vector_type(4))) float f32x4;

__device__ __forceinline__ unsigned short f2bf(float f) {
  union { float f; unsigned u; } c; c.f = f;
  unsigned r = c.u + 0x7fffu + ((c.u >> 16) & 1u);  // RNE
  return (unsigned short)(r >> 16);
}

__device__ __forceinline__ void gload_lds16(const void* g, void* l) {
  __builtin_amdgcn_global_load_lds(
      (const __attribute__((address_space(1))) void*)g,
      (__attribute__((address_space(3))) void*)l, 16, 0, 0);
}

// ---------------- gating: probs[b,e] = softmax(x @ Wg + bg) ----------------
__global__ __launch_bounds__(256) void gating_kernel(
    const float* __restrict__ x, const float* __restrict__ Wg,
    const float* __restrict__ bg, float* __restrict__ probs)
{
  __shared__ float sWg[D_DIM * E_DIM];  // 32 KB
  for (int i = threadIdx.x; i < D_DIM * E_DIM; i += 256) sWg[i] = Wg[i];
  __syncthreads();

  const int wave = threadIdx.x >> 6, lane = threadIdx.x & 63;
  const int b = blockIdx.x * 4 + wave;

  float acc[E_DIM] = {};
  const float* xr = x + (size_t)b * D_DIM;
  #pragma unroll
  for (int i = 0; i < D_DIM / 64; ++i) {
    int d = i * 64 + lane;
    float xv = xr[d];
    #pragma unroll
    for (int e = 0; e < E_DIM; ++e) acc[e] += xv * sWg[d * E_DIM + e];
  }
  #pragma unroll
  for (int e = 0; e < E_DIM; ++e) {
    #pragma unroll
    for (int off = 32; off > 0; off >>= 1) acc[e] += __shfl_down(acc[e], off);
  }
  if (lane == 0) {
    float m = -1e30f;
    #pragma unroll
    for (int e = 0; e < E_DIM; ++e) { acc[e] += bg[e]; m = fmaxf(m, acc[e]); }
    float p[E_DIM]; float s = 0.f;
    #pragma unroll
    for (int e = 0; e < E_DIM; ++e) { p[e] = expf(acc[e] - m); s += p[e]; }
    float inv = 1.0f / s;
    #pragma unroll
    for (int e = 0; e < E_DIM; ++e) probs[(size_t)b * E_DIM + e] = p[e] * inv;
  }
}

// ---------------- x (fp32) -> xb (bf16), same layout ----------------
__global__ __launch_bounds__(256) void convert_x_kernel(
    const float* __restrict__ x, unsigned short* __restrict__ xb)
{
  int i = blockIdx.x * 256 + threadIdx.x;  // one float4 per thread
  const float4* src = (const float4*)x;
  float4 v = src[i];
  union { unsigned short u[4]; unsigned long long q; } o;
  o.u[0] = f2bf(v.x); o.u[1] = f2bf(v.y); o.u[2] = f2bf(v.z); o.u[3] = f2bf(v.w);
  *(unsigned long long*)(xb + (size_t)i * 4) = o.q;
}

// ---------------- W1 [E][D][H] fp32 -> W1t [(e*H+h)][D] bf16 ----------------
__global__ __launch_bounds__(256) void transpose_w1(
    const float* __restrict__ W1, unsigned short* __restrict__ W1t)
{
  __shared__ float t[32][33];
  const int e = blockIdx.z;
  const int d0 = blockIdx.y * 32;   // over D
  const int h0 = blockIdx.x * 32;   // over H
  const int tx = threadIdx.x & 31, ty = threadIdx.x >> 5;
  const float* src = W1 + (size_t)e * D_DIM * H_DIM;
  #pragma unroll
  for (int i = 0; i < 4; ++i)
    t[ty + 8 * i][tx] = src[(size_t)(d0 + ty + 8 * i) * H_DIM + h0 + tx];
  __syncthreads();
  #pragma unroll
  for (int i = 0; i < 4; ++i)
    W1t[((size_t)e * H_DIM + h0 + ty + 8 * i) * D_DIM + d0 + tx] =
        f2bf(t[tx][ty + 8 * i]);
}

// ---------------- W2 [E][H][O] fp32 -> W2t [O][E*H] bf16 ----------------
__global__ __launch_bounds__(256) void transpose_w2(
    const float* __restrict__ W2, unsigned short* __restrict__ W2t)
{
  __shared__ float t[32][33];
  const int e = blockIdx.z;
  const int h0 = blockIdx.y * 32;   // over H
  const int o0 = blockIdx.x * 32;   // over O
  const int tx = threadIdx.x & 31, ty = threadIdx.x >> 5;
  const float* src = W2 + (size_t)e * H_DIM * O_DIM;
  #pragma unroll
  for (int i = 0; i < 4; ++i)
    t[ty + 8 * i][tx] = src[(size_t)(h0 + ty + 8 * i) * O_DIM + o0 + tx];
  __syncthreads();
  #pragma unroll
  for (int i = 0; i < 4; ++i)
    W2t[(size_t)(o0 + ty + 8 * i) * KTOT + (size_t)e * H_DIM + h0 + tx] =
        f2bf(t[tx][ty + 8 * i]);
}

// ---------------- GEMM C = A[M,K] * Bt[N,K]^T  (m97 structure) ----------------
// MODE 1: Cout = bf16( relu(acc + b1[col]) * probs[row, col>>12] ), stride N
// MODE 2: Cout = fp32( acc + sum_e probs[row,e]*b2[e,col] ), stride N
template<int BM, int BN, int MODE>
__global__ __launch_bounds__(256)
void gemm_bt(const unsigned short* __restrict__ A,
             const unsigned short* __restrict__ Bt,
             void* __restrict__ Cout,
             const float* __restrict__ probs,
             const float* __restrict__ bias,
             int M, int N, int K)
{
  constexpr int BKc = 64;
  constexpr int MR = BM / 32, NR = BN / 32;  // per-wave 16x16 fragments (2x2 wave grid)
  __shared__ __align__(16) unsigned short lA[BM * BKc];
  __shared__ __align__(16) unsigned short lB[BN * BKc];

  const int mTiles = M / BM, nTiles = N / BN;
  int mt, nt;
  if (MODE == 1) { mt = blockIdx.x % mTiles; nt = blockIdx.x / mTiles; }  // m-fast: share B panel
  else           { nt = blockIdx.x % nTiles; mt = blockIdx.x / nTiles; }  // n-fast: share A panel

  const int tid = threadIdx.x;
  const int wave = tid >> 6, lane = tid & 63;
  const int wr = wave >> 1, wc = wave & 1;
  const size_t brow = (size_t)mt * BM, bcol = (size_t)nt * BN;

  f32x4 acc[MR][NR] = {};

  const char* Ab = (const char*)(A + brow * K);
  const char* Bb = (const char*)(Bt + bcol * K);
  const size_t rowBytes = (size_t)K * 2;

  constexpr int A_IT = BM * BKc * 2 / 4096;
  constexpr int B_IT = BN * BKc * 2 / 4096;

  for (int k0 = 0; k0 < K; k0 += BKc) {
    #pragma unroll
    for (int i = 0; i < A_IT; ++i) {
      int o = i * 4096 + tid * 16;
      int row = o >> 7, cb = o & 127;           // BKc*2 = 128 bytes per LDS row
      gload_lds16(Ab + (size_t)row * rowBytes + (size_t)k0 * 2 + cb, (char*)lA + o);
    }
    #pragma unroll
    for (int i = 0; i < B_IT; ++i) {
      int o = i * 4096 + tid * 16;
      int row = o >> 7, cb = o & 127;
      gload_lds16(Bb + (size_t)row * rowBytes + (size_t)k0 * 2 + cb, (char*)lB + o);
    }
    __syncthreads();

    #pragma unroll
    for (int kk = 0; kk < 2; ++kk) {
      bf16x8 af[MR], bfr[NR];
      #pragma unroll
      for (int m = 0; m < MR; ++m) {
        int r = wr * (BM / 2) + m * 16 + (lane & 15);
        af[m] = *(const bf16x8*)&lA[r * BKc + kk * 32 + (lane >> 4) * 8];
      }
      #pragma unroll
      for (int n = 0; n < NR; ++n) {
        int r = wc * (BN / 2) + n * 16 + (lane & 15);
        bfr[n] = *(const bf16x8*)&lB[r * BKc + kk * 32 + (lane >> 4) * 8];
      }
      #pragma unroll
      for (int m = 0; m < MR; ++m)
        #pragma unroll
        for (int n = 0; n < NR; ++n)
          acc[m][n] = __builtin_amdgcn_mfma_f32_16x16x32_bf16(af[m], bfr[n], acc[m][n], 0, 0, 0);
    }
    __syncthreads();
  }

  // epilogue: C/D layout col = lane&15, row = (lane>>4)*4 + j  [m89-verified]
  #pragma unroll
  for (int m = 0; m < MR; ++m) {
    #pragma unroll
    for (int n = 0; n < NR; ++n) {
      const int col = (int)bcol + wc * (BN / 2) + n * 16 + (lane & 15);
      #pragma unroll
      for (int j = 0; j < 4; ++j) {
        const int row = (int)brow + wr * (BM / 2) + m * 16 + ((lane >> 4) * 4) + j;
        float v = acc[m][n][j];
        if (MODE == 1) {
          v += bias[col];                       // b1 flat [E*H]
          v = fmaxf(v, 0.0f) * probs[row * E_DIM + (col >> 12)];
          ((unsigned short*)Cout)[(size_t)row * N + col] = f2bf(v);
        } else {
          float corr = 0.0f;
          #pragma unroll
          for (int e = 0; e < E_DIM; ++e)
            corr += probs[row * E_DIM + e] * bias[e * O_DIM + col];
          ((float*)Cout)[(size_t)row * N + col] = v + corr;
        }
      }
    }
  }
}

extern "C" void kernel_launch(void* const* d_in, const int* in_sizes, int n_in,
                              void* d_out, int out_size, void* d_ws, size_t ws_size,
                              hipStream_t stream)
{
  const float* x  = (const float*)d_in[0];
  const float* W1 = (const float*)d_in[1];
  const float* b1 = (const float*)d_in[2];
  const float* W2 = (const float*)d_in[3];
  const float* b2 = (const float*)d_in[4];
  const float* Wg = (const float*)d_in[5];
  const float* bg = (const float*)d_in[6];
  float* out = (float*)d_out;

  // workspace layout
  char* ws = (char*)d_ws;
  float*          probs = (float*)ws;                                   // 128 KB
  unsigned short* xb    = (unsigned short*)(ws + (1u << 17));           // 8 MB
  unsigned short* W1t   = (unsigned short*)(ws + (1u << 17) + (8u << 20));       // 64 MB
  unsigned short* W2t   = (unsigned short*)(ws + (1u << 17) + (8u << 20) + (64u << 20)); // 64 MB
  unsigned short* hp    = (unsigned short*)(ws + (1u << 17) + (8u << 20) + (128u << 20)); // 256 MB

  gating_kernel<<<B_DIM / 4, 256, 0, stream>>>(x, Wg, bg, probs);
  convert_x_kernel<<<(B_DIM * D_DIM / 4) / 256, 256, 0, stream>>>(x, xb);
  transpose_w1<<<dim3(H_DIM / 32, D_DIM / 32, E_DIM), 256, 0, stream>>>(W1, W1t);
  transpose_w2<<<dim3(O_DIM / 32, H_DIM / 32, E_DIM), 256, 0, stream>>>(W2, W2t);

  // GEMM1: h' = bf16(p * relu(x @ W1 + b1))   M=4096 N=32768 K=1024
  gemm_bt<128, 128, 1><<<(B_DIM / 128) * (KTOT / 128), 256, 0, stream>>>(
      xb, W1t, hp, probs, b1, B_DIM, KTOT, D_DIM);

  // GEMM2: out = h' @ W2 + sum_e p*b2          M=4096 N=1024 K=32768
  gemm_bt<64, 128, 2><<<(B_DIM / 64) * (O_DIM / 128), 256, 0, stream>>>(
      hp, W2t, out, probs, b2, B_DIM, O_DIM, KTOT);
}

// Round 3
// 1322.301 us; speedup vs baseline: 1.1594x; 1.1594x over previous
//
#include <hip/hip_runtime.h>
#include <hip/hip_bf16.h>

// MoE forward, B=4096 E=8 D=1024 H=4096 O=1024, fp32 in/out, bf16 MFMA compute.
//
// out = sum_e p[b,e] * (relu(x @ W1[e] + b1[e]) @ W2[e] + b2[e])
//     = (h' @ W2flat) + sum_e p[b,e]*b2[e]      with h'[b, e*H+h] = p[b,e]*relu(...)
//
// Stage A: gating probs (fp32), x->bf16, W1 -> W1t [E*H][D] bf16, W2 -> W2t [O][E*H] bf16
// Stage B: GEMM1 (M=4096,N=32768,K=1024) epilogue relu*p -> h' bf16
// Stage C: GEMM2 (M=4096,N=1024,K=32768) split-K=4 -> fp32 partials (aliases W1t)
// Stage D: reduce partials + sum_e p*b2 -> out fp32

#define B_DIM 4096
#define E_DIM 8
#define D_DIM 1024
#define H_DIM 4096
#define O_DIM 1024
#define KTOT  (E_DIM * H_DIM)   // 32768
#define KSPLIT 4

typedef __attribute__((ext_vector_type(8))) short bf16x8;
typedef __attribute__((ext_vector_type(4))) float f32x4;

__device__ __forceinline__ unsigned short f2bf(float f) {
  union { float f; unsigned u; } c; c.f = f;
  unsigned r = c.u + 0x7fffu + ((c.u >> 16) & 1u);  // RNE
  return (unsigned short)(r >> 16);
}

__device__ __forceinline__ void gload_lds16(const void* g, void* l) {
  __builtin_amdgcn_global_load_lds(
      (const __attribute__((address_space(1))) void*)g,
      (__attribute__((address_space(3))) void*)l, 16, 0, 0);
}

// ---------------- gating: probs[b,e] = softmax(x @ Wg + bg) ----------------
__global__ __launch_bounds__(256) void gating_kernel(
    const float* __restrict__ x, const float* __restrict__ Wg,
    const float* __restrict__ bg, float* __restrict__ probs)
{
  __shared__ float sWg[D_DIM * E_DIM];  // 32 KB
  for (int i = threadIdx.x; i < D_DIM * E_DIM; i += 256) sWg[i] = Wg[i];
  __syncthreads();

  const int wave = threadIdx.x >> 6, lane = threadIdx.x & 63;
  const int b = blockIdx.x * 4 + wave;

  float acc[E_DIM] = {};
  const float* xr = x + (size_t)b * D_DIM;
  #pragma unroll
  for (int i = 0; i < D_DIM / 64; ++i) {
    int d = i * 64 + lane;
    float xv = xr[d];
    #pragma unroll
    for (int e = 0; e < E_DIM; ++e) acc[e] += xv * sWg[d * E_DIM + e];
  }
  #pragma unroll
  for (int e = 0; e < E_DIM; ++e) {
    #pragma unroll
    for (int off = 32; off > 0; off >>= 1) acc[e] += __shfl_down(acc[e], off);
  }
  if (lane == 0) {
    float m = -1e30f;
    #pragma unroll
    for (int e = 0; e < E_DIM; ++e) { acc[e] += bg[e]; m = fmaxf(m, acc[e]); }
    float p[E_DIM]; float s = 0.f;
    #pragma unroll
    for (int e = 0; e < E_DIM; ++e) { p[e] = expf(acc[e] - m); s += p[e]; }
    float inv = 1.0f / s;
    #pragma unroll
    for (int e = 0; e < E_DIM; ++e) probs[(size_t)b * E_DIM + e] = p[e] * inv;
  }
}

// ---------------- x (fp32) -> xb (bf16), same layout ----------------
__global__ __launch_bounds__(256) void convert_x_kernel(
    const float* __restrict__ x, unsigned short* __restrict__ xb)
{
  int i = blockIdx.x * 256 + threadIdx.x;  // one float4 per thread
  const float4* src = (const float4*)x;
  float4 v = src[i];
  union { unsigned short u[4]; unsigned long long q; } o;
  o.u[0] = f2bf(v.x); o.u[1] = f2bf(v.y); o.u[2] = f2bf(v.z); o.u[3] = f2bf(v.w);
  *(unsigned long long*)(xb + (size_t)i * 4) = o.q;
}

// ---------------- W1 [E][D][H] fp32 -> W1t [(e*H+h)][D] bf16 ----------------
__global__ __launch_bounds__(256) void transpose_w1(
    const float* __restrict__ W1, unsigned short* __restrict__ W1t)
{
  __shared__ float t[32][33];
  const int e = blockIdx.z;
  const int d0 = blockIdx.y * 32;   // over D
  const int h0 = blockIdx.x * 32;   // over H
  const int tx = threadIdx.x & 31, ty = threadIdx.x >> 5;
  const float* src = W1 + (size_t)e * D_DIM * H_DIM;
  #pragma unroll
  for (int i = 0; i < 4; ++i)
    t[ty + 8 * i][tx] = src[(size_t)(d0 + ty + 8 * i) * H_DIM + h0 + tx];
  __syncthreads();
  #pragma unroll
  for (int i = 0; i < 4; ++i)
    W1t[((size_t)e * H_DIM + h0 + ty + 8 * i) * D_DIM + d0 + tx] =
        f2bf(t[tx][ty + 8 * i]);
}

// ---------------- W2 [E][H][O] fp32 -> W2t [O][E*H] bf16 ----------------
__global__ __launch_bounds__(256) void transpose_w2(
    const float* __restrict__ W2, unsigned short* __restrict__ W2t)
{
  __shared__ float t[32][33];
  const int e = blockIdx.z;
  const int h0 = blockIdx.y * 32;   // over H
  const int o0 = blockIdx.x * 32;   // over O
  const int tx = threadIdx.x & 31, ty = threadIdx.x >> 5;
  const float* src = W2 + (size_t)e * H_DIM * O_DIM;
  #pragma unroll
  for (int i = 0; i < 4; ++i)
    t[ty + 8 * i][tx] = src[(size_t)(h0 + ty + 8 * i) * O_DIM + o0 + tx];
  __syncthreads();
  #pragma unroll
  for (int i = 0; i < 4; ++i)
    W2t[(size_t)(o0 + ty + 8 * i) * KTOT + (size_t)e * H_DIM + h0 + tx] =
        f2bf(t[tx][ty + 8 * i]);
}

// ---------------- GEMM C = A[M,K] * Bt[N,K]^T  (m97 structure) ----------------
// MODE 1: Cout = bf16( relu(acc + b1[col]) * probs[row, col>>12] ), stride N
// MODE 2: fp32 partial write to Cout + blockIdx.y*M*N (split-K), stride N
template<int BM, int BN, int MODE>
__global__ __launch_bounds__(256)
void gemm_bt(const unsigned short* __restrict__ A,
             const unsigned short* __restrict__ Bt,
             void* __restrict__ Cout,
             const float* __restrict__ probs,
             const float* __restrict__ bias,
             int M, int N, int K, int kChunk)
{
  constexpr int BKc = 64;
  constexpr int MR = BM / 32, NR = BN / 32;  // per-wave 16x16 fragments (2x2 wave grid)
  __shared__ __align__(16) unsigned short lA[BM * BKc];
  __shared__ __align__(16) unsigned short lB[BN * BKc];

  const int mTiles = M / BM, nTiles = N / BN;
  int mt, nt;
  if (MODE == 1) { mt = blockIdx.x % mTiles; nt = blockIdx.x / mTiles; }  // m-fast: share B panel
  else           { nt = blockIdx.x % nTiles; mt = blockIdx.x / nTiles; }  // n-fast: share A panel

  const int tid = threadIdx.x;
  const int wave = tid >> 6, lane = tid & 63;
  const int wr = wave >> 1, wc = wave & 1;
  const size_t brow = (size_t)mt * BM, bcol = (size_t)nt * BN;

  f32x4 acc[MR][NR] = {};

  const char* Ab = (const char*)(A + brow * K);
  const char* Bb = (const char*)(Bt + bcol * K);
  const size_t rowBytes = (size_t)K * 2;

  constexpr int A_IT = BM * BKc * 2 / 4096;
  constexpr int B_IT = BN * BKc * 2 / 4096;

  const int kBeg = blockIdx.y * kChunk;
  const int kEnd = kBeg + kChunk;

  for (int k0 = kBeg; k0 < kEnd; k0 += BKc) {
    #pragma unroll
    for (int i = 0; i < A_IT; ++i) {
      int o = i * 4096 + tid * 16;
      int row = o >> 7, cb = o & 127;           // BKc*2 = 128 bytes per LDS row
      gload_lds16(Ab + (size_t)row * rowBytes + (size_t)k0 * 2 + cb, (char*)lA + o);
    }
    #pragma unroll
    for (int i = 0; i < B_IT; ++i) {
      int o = i * 4096 + tid * 16;
      int row = o >> 7, cb = o & 127;
      gload_lds16(Bb + (size_t)row * rowBytes + (size_t)k0 * 2 + cb, (char*)lB + o);
    }
    __syncthreads();

    #pragma unroll
    for (int kk = 0; kk < 2; ++kk) {
      bf16x8 af[MR], bfr[NR];
      #pragma unroll
      for (int m = 0; m < MR; ++m) {
        int r = wr * (BM / 2) + m * 16 + (lane & 15);
        af[m] = *(const bf16x8*)&lA[r * BKc + kk * 32 + (lane >> 4) * 8];
      }
      #pragma unroll
      for (int n = 0; n < NR; ++n) {
        int r = wc * (BN / 2) + n * 16 + (lane & 15);
        bfr[n] = *(const bf16x8*)&lB[r * BKc + kk * 32 + (lane >> 4) * 8];
      }
      #pragma unroll
      for (int m = 0; m < MR; ++m)
        #pragma unroll
        for (int n = 0; n < NR; ++n)
          acc[m][n] = __builtin_amdgcn_mfma_f32_16x16x32_bf16(af[m], bfr[n], acc[m][n], 0, 0, 0);
    }
    __syncthreads();
  }

  // epilogue: C/D layout col = lane&15, row = (lane>>4)*4 + j  [m89-verified]
  #pragma unroll
  for (int m = 0; m < MR; ++m) {
    #pragma unroll
    for (int n = 0; n < NR; ++n) {
      const int col = (int)bcol + wc * (BN / 2) + n * 16 + (lane & 15);
      #pragma unroll
      for (int j = 0; j < 4; ++j) {
        const int row = (int)brow + wr * (BM / 2) + m * 16 + ((lane >> 4) * 4) + j;
        float v = acc[m][n][j];
        if (MODE == 1) {
          v += bias[col];                       // b1 flat [E*H]
          v = fmaxf(v, 0.0f) * probs[row * E_DIM + (col >> 12)];
          ((unsigned short*)Cout)[(size_t)row * N + col] = f2bf(v);
        } else {
          float* dst = (float*)Cout + (size_t)blockIdx.y * M * N;
          dst[(size_t)row * N + col] = v;
        }
      }
    }
  }
}

// ---------------- reduce split-K partials + bias correction ----------------
__global__ __launch_bounds__(256) void reduce_out(
    const float* __restrict__ partial, const float* __restrict__ probs,
    const float* __restrict__ b2, float* __restrict__ out)
{
  const int i = blockIdx.x * 256 + threadIdx.x;        // over B*O/4 float4s
  const int row = i >> 8;                              // O/4 = 256 float4 per row
  const int colv = i & 255;
  const size_t plane = (size_t)B_DIM * O_DIM / 4;

  float4 v = make_float4(0.f, 0.f, 0.f, 0.f);
  #pragma unroll
  for (int ks = 0; ks < KSPLIT; ++ks) {
    float4 p = ((const float4*)partial)[ks * plane + i];
    v.x += p.x; v.y += p.y; v.z += p.z; v.w += p.w;
  }
  #pragma unroll
  for (int e = 0; e < E_DIM; ++e) {
    float pe = probs[row * E_DIM + e];
    float4 b = ((const float4*)b2)[e * (O_DIM / 4) + colv];
    v.x += pe * b.x; v.y += pe * b.y; v.z += pe * b.z; v.w += pe * b.w;
  }
  ((float4*)out)[i] = v;
}

extern "C" void kernel_launch(void* const* d_in, const int* in_sizes, int n_in,
                              void* d_out, int out_size, void* d_ws, size_t ws_size,
                              hipStream_t stream)
{
  const float* x  = (const float*)d_in[0];
  const float* W1 = (const float*)d_in[1];
  const float* b1 = (const float*)d_in[2];
  const float* W2 = (const float*)d_in[3];
  const float* b2 = (const float*)d_in[4];
  const float* Wg = (const float*)d_in[5];
  const float* bg = (const float*)d_in[6];
  float* out = (float*)d_out;

  // workspace layout
  char* ws = (char*)d_ws;
  float*          probs = (float*)ws;                                   // 128 KB
  unsigned short* xb    = (unsigned short*)(ws + (1u << 17));           // 8 MB
  unsigned short* W1t   = (unsigned short*)(ws + (1u << 17) + (8u << 20));       // 64 MB
  unsigned short* W2t   = (unsigned short*)(ws + (1u << 17) + (8u << 20) + (64u << 20)); // 64 MB
  unsigned short* hp    = (unsigned short*)(ws + (1u << 17) + (8u << 20) + (128u << 20)); // 256 MB
  // split-K partials alias W1t (dead after GEMM1): 4 x 16 MB fp32 = 64 MB
  float* partial = (float*)W1t;

  gating_kernel<<<B_DIM / 4, 256, 0, stream>>>(x, Wg, bg, probs);
  convert_x_kernel<<<(B_DIM * D_DIM / 4) / 256, 256, 0, stream>>>(x, xb);
  transpose_w1<<<dim3(H_DIM / 32, D_DIM / 32, E_DIM), 256, 0, stream>>>(W1, W1t);
  transpose_w2<<<dim3(O_DIM / 32, H_DIM / 32, E_DIM), 256, 0, stream>>>(W2, W2t);

  // GEMM1: h' = bf16(p * relu(x @ W1 + b1))   M=4096 N=32768 K=1024
  gemm_bt<128, 128, 1><<<dim3((B_DIM / 128) * (KTOT / 128), 1), 256, 0, stream>>>(
      xb, W1t, hp, probs, b1, B_DIM, KTOT, D_DIM, D_DIM);

  // GEMM2: partial[ks] = h' @ W2 (chunk ks)    M=4096 N=1024 K=32768, split-K=4
  gemm_bt<128, 128, 2><<<dim3((B_DIM / 128) * (O_DIM / 128), KSPLIT), 256, 0, stream>>>(
      hp, W2t, partial, probs, nullptr, B_DIM, O_DIM, KTOT, KTOT / KSPLIT);

  // reduce partials + sum_e p*b2 -> out
  reduce_out<<<(B_DIM * O_DIM / 4) / 256, 256, 0, stream>>>(partial, probs, b2, out);
}

// Round 4
// 1060.008 us; speedup vs baseline: 1.4463x; 1.2474x over previous
//
#include <hip/hip_runtime.h>
#include <hip/hip_bf16.h>

// MoE forward, B=4096 E=8 D=1024 H=4096 O=1024, fp32 in/out, bf16 MFMA compute.
//
// out = sum_e p[b,e] * (relu(x @ W1[e] + b1[e]) @ W2[e] + b2[e])
//     = (h' @ W2flat) + sum_e p[b,e]*b2[e]      with h'[b, e*H+h] = p[b,e]*relu(...)
//
// GEMMs use the 256x256 8-phase template (m201): BK=64, 512 threads (8 waves 2Mx4N),
// 128KB LDS double-buffer in 4x16KB half-tile segments, st_16x32 XOR swizzle,
// counted vmcnt(8) at phases 4/8, setprio around MFMA clusters, XCD-aware swizzle.

#define B_DIM 4096
#define E_DIM 8
#define D_DIM 1024
#define H_DIM 4096
#define O_DIM 1024
#define KTOT  (E_DIM * H_DIM)   // 32768
#define KSPLIT 4

typedef __attribute__((ext_vector_type(8))) short bf16x8;
typedef __attribute__((ext_vector_type(4))) float f32x4;

__device__ __forceinline__ unsigned short f2bf(float f) {
  union { float f; unsigned u; } c; c.f = f;
  unsigned r = c.u + 0x7fffu + ((c.u >> 16) & 1u);  // RNE
  return (unsigned short)(r >> 16);
}

__device__ __forceinline__ void gload_lds16(const void* g, void* l) {
  __builtin_amdgcn_global_load_lds(
      (const __attribute__((address_space(1))) void*)g,
      (__attribute__((address_space(3))) void*)l, 16, 0, 0);
}

__device__ __forceinline__ void barfence() {
  asm volatile("" ::: "memory");
  __builtin_amdgcn_s_barrier();
  asm volatile("" ::: "memory");
}

// st_16x32 swizzle within each 1024B subtile (m201/m204 verified)
__device__ __forceinline__ unsigned swz16(unsigned o) {
  return o ^ (((o >> 9) & 1u) << 5);
}

// Stage one 128x64 bf16 half-tile (16KB) into LDS segment `seg`.
// LDS dest is linear (base + lane*16); global source is pre-inverse-swizzled
// so that swizzled ds_reads see the right data (G21 both-sides rule).
__device__ __forceinline__ void stageHalf(const char* gbase, size_t rowBytes, int kByte,
                                          char* seg, int tid) {
  #pragma unroll
  for (int r = 0; r < 2; ++r) {
    unsigned o = (unsigned)((r * 512 + tid) * 16);
    unsigned q = swz16(o);
    gload_lds16(gbase + (size_t)(q >> 7) * rowBytes + kByte + (q & 127), seg + o);
  }
}

// ---- one K-tile (BK=64) = 4 phases; quadrant order (0,0),(0,1),(1,1),(1,0) ----
template<bool STAGE, int VMN>
__device__ __forceinline__ void tile4(
    char* smem, int bufOff,
    const char* AbC, const char* BbC, size_t rbA, size_t rbB, int kStage,
    int wm, int wn, int lane, int tid, f32x4 (&acc)[8][4])
{
  bf16x8 aF[4][2], bLo[2][2], bHi[2][2];
  const char* aSeg = smem + bufOff + wm * 16384;            // A-half = wm
  const char* bSeg = smem + bufOff + (2 + (wn >> 1)) * 16384; // B-half = wn>>1

  // ---------- P1: quadrant (0,0) ----------
  #pragma unroll
  for (int m = 0; m < 4; ++m)
    #pragma unroll
    for (int kk = 0; kk < 2; ++kk) {
      unsigned o = (unsigned)((m * 16 + (lane & 15)) * 128 + kk * 64 + ((lane >> 4) * 16));
      aF[m][kk] = *(const bf16x8*)(aSeg + swz16(o));
    }
  #pragma unroll
  for (int n = 0; n < 2; ++n)
    #pragma unroll
    for (int kk = 0; kk < 2; ++kk) {
      unsigned o = (unsigned)(((wn & 1) * 64 + n * 16 + (lane & 15)) * 128 + kk * 64 + ((lane >> 4) * 16));
      bLo[n][kk] = *(const bf16x8*)(bSeg + swz16(o));
    }
  asm volatile("s_waitcnt lgkmcnt(8)" ::: "memory");
  barfence();
  asm volatile("s_waitcnt lgkmcnt(0)" ::: "memory");
  __builtin_amdgcn_s_setprio(1);
  #pragma unroll
  for (int m = 0; m < 4; ++m)
    #pragma unroll
    for (int n = 0; n < 2; ++n)
      #pragma unroll
      for (int kk = 0; kk < 2; ++kk)
        acc[m][n] = __builtin_amdgcn_mfma_f32_16x16x32_bf16(aF[m][kk], bLo[n][kk], acc[m][n], 0, 0, 0);
  __builtin_amdgcn_s_setprio(0);
  barfence();

  // ---------- P2: quadrant (0,1) ----------
  #pragma unroll
  for (int n = 0; n < 2; ++n)
    #pragma unroll
    for (int kk = 0; kk < 2; ++kk) {
      unsigned o = (unsigned)(((wn & 1) * 64 + (2 + n) * 16 + (lane & 15)) * 128 + kk * 64 + ((lane >> 4) * 16));
      bHi[n][kk] = *(const bf16x8*)(bSeg + swz16(o));
    }
  barfence();
  asm volatile("s_waitcnt lgkmcnt(0)" ::: "memory");
  __builtin_amdgcn_s_setprio(1);
  #pragma unroll
  for (int m = 0; m < 4; ++m)
    #pragma unroll
    for (int n = 0; n < 2; ++n)
      #pragma unroll
      for (int kk = 0; kk < 2; ++kk)
        acc[m][2 + n] = __builtin_amdgcn_mfma_f32_16x16x32_bf16(aF[m][kk], bHi[n][kk], acc[m][2 + n], 0, 0, 0);
  __builtin_amdgcn_s_setprio(0);
  barfence();

  // ---------- P3: quadrant (1,1); stage next-tile B halves ----------
  #pragma unroll
  for (int m = 0; m < 4; ++m)
    #pragma unroll
    for (int kk = 0; kk < 2; ++kk) {
      unsigned o = (unsigned)(((4 + m) * 16 + (lane & 15)) * 128 + kk * 64 + ((lane >> 4) * 16));
      aF[m][kk] = *(const bf16x8*)(aSeg + swz16(o));
    }
  if (STAGE) {
    stageHalf(BbC,                    rbB, kStage, smem + bufOff + 2 * 16384, tid);
    stageHalf(BbC + (size_t)128 * rbB, rbB, kStage, smem + bufOff + 3 * 16384, tid);
  }
  barfence();
  asm volatile("s_waitcnt lgkmcnt(0)" ::: "memory");
  __builtin_amdgcn_s_setprio(1);
  #pragma unroll
  for (int m = 0; m < 4; ++m)
    #pragma unroll
    for (int n = 0; n < 2; ++n)
      #pragma unroll
      for (int kk = 0; kk < 2; ++kk)
        acc[4 + m][2 + n] = __builtin_amdgcn_mfma_f32_16x16x32_bf16(aF[m][kk], bHi[n][kk], acc[4 + m][2 + n], 0, 0, 0);
  __builtin_amdgcn_s_setprio(0);
  barfence();

  // ---------- P4: quadrant (1,0); stage next-tile A halves; counted vmcnt ----------
  if (STAGE) {
    stageHalf(AbC,                    rbA, kStage, smem + bufOff + 0,     tid);
    stageHalf(AbC + (size_t)128 * rbA, rbA, kStage, smem + bufOff + 16384, tid);
  }
  if (VMN == 8)      asm volatile("s_waitcnt vmcnt(8)" ::: "memory");
  else if (VMN == 0) asm volatile("s_waitcnt vmcnt(0)" ::: "memory");
  barfence();
  __builtin_amdgcn_s_setprio(1);
  #pragma unroll
  for (int m = 0; m < 4; ++m)
    #pragma unroll
    for (int n = 0; n < 2; ++n)
      #pragma unroll
      for (int kk = 0; kk < 2; ++kk)
        acc[4 + m][n] = __builtin_amdgcn_mfma_f32_16x16x32_bf16(aF[m][kk], bLo[n][kk], acc[4 + m][n], 0, 0, 0);
  __builtin_amdgcn_s_setprio(0);
  barfence();
}

// ---------------- 256x256 8-phase GEMM  C = A[M,K] * Bt[N,K]^T ----------------
// MODE 1: Cout = bf16( relu(acc + b1[col]) * probs[row, col>>12] ), N=32768
// MODE 2: fp32 partial write to Cout + blockIdx.y*M*N (split-K), N=1024
template<int MODE>
__global__ __launch_bounds__(512, 2)
void gemm8p(const unsigned short* __restrict__ A,
            const unsigned short* __restrict__ Bt,
            void* __restrict__ Cout,
            const float* __restrict__ probs,
            const float* __restrict__ bias,
            int M, int N, int K, int kChunk)
{
  __shared__ __align__(16) char smem[131072];  // 2 buf x (A0,A1,B0,B1) x 16KB

  const int tid = threadIdx.x;
  const int wave = tid >> 6, lane = tid & 63;
  const int wm = wave >> 2, wn = wave & 3;

  int mt, nt, kBeg;
  if (MODE == 1) {
    // 2048 blocks, XCD-chunked bijective swizzle, m-fast (16 m-tiles share B panel per XCD)
    int bid = blockIdx.x;
    int swz = (bid & 7) * 256 + (bid >> 3);
    mt = swz & 15; nt = swz >> 4; kBeg = 0;
  } else {
    // 64 x-blocks: put the 4 nt-blocks sharing an A panel on one XCD
    int x = blockIdx.x;
    mt = (x & 7) * 2 + ((x >> 3) & 1);
    nt = x >> 4;
    kBeg = blockIdx.y * kChunk;
  }

  const char* AbC = (const char*)(A + (size_t)mt * 256 * K);
  const char* BbC = (const char*)(Bt + (size_t)nt * 256 * K);
  const size_t rbA = (size_t)K * 2, rbB = (size_t)K * 2;

  f32x4 acc[8][4] = {};

  const int NT = kChunk / 64;   // K-tiles (even, >= 4)
  const int NI = NT / 2;

  // prologue: stage tile0 -> buf0, tile1 -> buf1 (order: B,B,A,A per tile)
  {
    int k0 = kBeg * 2, k1 = (kBeg + 64) * 2;
    stageHalf(BbC,                    rbB, k0, smem + 2 * 16384, tid);
    stageHalf(BbC + (size_t)128 * rbB, rbB, k0, smem + 3 * 16384, tid);
    stageHalf(AbC,                    rbA, k0, smem + 0,         tid);
    stageHalf(AbC + (size_t)128 * rbA, rbA, k0, smem + 16384,    tid);
    stageHalf(BbC,                    rbB, k1, smem + 65536 + 2 * 16384, tid);
    stageHalf(BbC + (size_t)128 * rbB, rbB, k1, smem + 65536 + 3 * 16384, tid);
    stageHalf(AbC,                    rbA, k1, smem + 65536 + 0,         tid);
    stageHalf(AbC + (size_t)128 * rbA, rbA, k1, smem + 65536 + 16384,    tid);
  }
  asm volatile("s_waitcnt vmcnt(8)" ::: "memory");  // tile0 landed
  barfence();

  for (int i = 0; i < NI - 1; ++i) {
    int ks0 = (kBeg + (2 * i + 2) * 64) * 2;
    int ks1 = (kBeg + (2 * i + 3) * 64) * 2;
    tile4<true, 8>(smem, 0,     AbC, BbC, rbA, rbB, ks0, wm, wn, lane, tid, acc);
    tile4<true, 8>(smem, 65536, AbC, BbC, rbA, rbB, ks1, wm, wn, lane, tid, acc);
  }
  // peeled last iteration: no staging; drain remaining loads before buf1 use
  tile4<false, 0>(smem, 0,     AbC, BbC, rbA, rbB, 0, wm, wn, lane, tid, acc);
  tile4<false, -1>(smem, 65536, AbC, BbC, rbA, rbB, 0, wm, wn, lane, tid, acc);

  // epilogue: C/D layout col = lane&15, row = (lane>>4)*4 + j  [m89-verified]
  const int colBase = nt * 256 + wn * 64;
  const int rowBase = mt * 256 + wm * 128;
  #pragma unroll
  for (int m = 0; m < 8; ++m) {
    #pragma unroll
    for (int n = 0; n < 4; ++n) {
      const int col = colBase + n * 16 + (lane & 15);
      #pragma unroll
      for (int j = 0; j < 4; ++j) {
        const int row = rowBase + m * 16 + ((lane >> 4) * 4) + j;
        float v = acc[m][n][j];
        if (MODE == 1) {
          v += bias[col];
          v = fmaxf(v, 0.0f) * probs[row * E_DIM + (col >> 12)];
          ((unsigned short*)Cout)[(size_t)row * N + col] = f2bf(v);
        } else {
          float* dst = (float*)Cout + (size_t)blockIdx.y * M * N;
          dst[(size_t)row * N + col] = v;
        }
      }
    }
  }
}

// ---------------- gating: probs[b,e] = softmax(x @ Wg + bg) ----------------
__global__ __launch_bounds__(256) void gating_kernel(
    const float* __restrict__ x, const float* __restrict__ Wg,
    const float* __restrict__ bg, float* __restrict__ probs)
{
  __shared__ float sWg[D_DIM * E_DIM];  // 32 KB
  for (int i = threadIdx.x; i < D_DIM * E_DIM; i += 256) sWg[i] = Wg[i];
  __syncthreads();

  const int wave = threadIdx.x >> 6, lane = threadIdx.x & 63;
  const int b = blockIdx.x * 4 + wave;

  float acc[E_DIM] = {};
  const float* xr = x + (size_t)b * D_DIM;
  #pragma unroll
  for (int i = 0; i < D_DIM / 64; ++i) {
    int d = i * 64 + lane;
    float xv = xr[d];
    #pragma unroll
    for (int e = 0; e < E_DIM; ++e) acc[e] += xv * sWg[d * E_DIM + e];
  }
  #pragma unroll
  for (int e = 0; e < E_DIM; ++e) {
    #pragma unroll
    for (int off = 32; off > 0; off >>= 1) acc[e] += __shfl_down(acc[e], off);
  }
  if (lane == 0) {
    float m = -1e30f;
    #pragma unroll
    for (int e = 0; e < E_DIM; ++e) { acc[e] += bg[e]; m = fmaxf(m, acc[e]); }
    float p[E_DIM]; float s = 0.f;
    #pragma unroll
    for (int e = 0; e < E_DIM; ++e) { p[e] = expf(acc[e] - m); s += p[e]; }
    float inv = 1.0f / s;
    #pragma unroll
    for (int e = 0; e < E_DIM; ++e) probs[(size_t)b * E_DIM + e] = p[e] * inv;
  }
}

// ---------------- x (fp32) -> xb (bf16), same layout ----------------
__global__ __launch_bounds__(256) void convert_x_kernel(
    const float* __restrict__ x, unsigned short* __restrict__ xb)
{
  int i = blockIdx.x * 256 + threadIdx.x;  // one float4 per thread
  const float4* src = (const float4*)x;
  float4 v = src[i];
  union { unsigned short u[4]; unsigned long long q; } o;
  o.u[0] = f2bf(v.x); o.u[1] = f2bf(v.y); o.u[2] = f2bf(v.z); o.u[3] = f2bf(v.w);
  *(unsigned long long*)(xb + (size_t)i * 4) = o.q;
}

// ---------------- W1 [E][D][H] fp32 -> W1t [(e*H+h)][D] bf16 ----------------
__global__ __launch_bounds__(256) void transpose_w1(
    const float* __restrict__ W1, unsigned short* __restrict__ W1t)
{
  __shared__ float t[32][33];
  const int e = blockIdx.z;
  const int d0 = blockIdx.y * 32;   // over D
  const int h0 = blockIdx.x * 32;   // over H
  const int tx = threadIdx.x & 31, ty = threadIdx.x >> 5;
  const float* src = W1 + (size_t)e * D_DIM * H_DIM;
  #pragma unroll
  for (int i = 0; i < 4; ++i)
    t[ty + 8 * i][tx] = src[(size_t)(d0 + ty + 8 * i) * H_DIM + h0 + tx];
  __syncthreads();
  #pragma unroll
  for (int i = 0; i < 4; ++i)
    W1t[((size_t)e * H_DIM + h0 + ty + 8 * i) * D_DIM + d0 + tx] =
        f2bf(t[tx][ty + 8 * i]);
}

// ---------------- W2 [E][H][O] fp32 -> W2t [O][E*H] bf16 ----------------
__global__ __launch_bounds__(256) void transpose_w2(
    const float* __restrict__ W2, unsigned short* __restrict__ W2t)
{
  __shared__ float t[32][33];
  const int e = blockIdx.z;
  const int h0 = blockIdx.y * 32;   // over H
  const int o0 = blockIdx.x * 32;   // over O
  const int tx = threadIdx.x & 31, ty = threadIdx.x >> 5;
  const float* src = W2 + (size_t)e * H_DIM * O_DIM;
  #pragma unroll
  for (int i = 0; i < 4; ++i)
    t[ty + 8 * i][tx] = src[(size_t)(h0 + ty + 8 * i) * O_DIM + o0 + tx];
  __syncthreads();
  #pragma unroll
  for (int i = 0; i < 4; ++i)
    W2t[(size_t)(o0 + ty + 8 * i) * KTOT + (size_t)e * H_DIM + h0 + tx] =
        f2bf(t[tx][ty + 8 * i]);
}

// ---------------- reduce split-K partials + bias correction ----------------
__global__ __launch_bounds__(256) void reduce_out(
    const float* __restrict__ partial, const float* __restrict__ probs,
    const float* __restrict__ b2, float* __restrict__ out)
{
  const int i = blockIdx.x * 256 + threadIdx.x;        // over B*O/4 float4s
  const int row = i >> 8;                              // O/4 = 256 float4 per row
  const int colv = i & 255;
  const size_t plane = (size_t)B_DIM * O_DIM / 4;

  float4 v = make_float4(0.f, 0.f, 0.f, 0.f);
  #pragma unroll
  for (int ks = 0; ks < KSPLIT; ++ks) {
    float4 p = ((const float4*)partial)[ks * plane + i];
    v.x += p.x; v.y += p.y; v.z += p.z; v.w += p.w;
  }
  #pragma unroll
  for (int e = 0; e < E_DIM; ++e) {
    float pe = probs[row * E_DIM + e];
    float4 b = ((const float4*)b2)[e * (O_DIM / 4) + colv];
    v.x += pe * b.x; v.y += pe * b.y; v.z += pe * b.z; v.w += pe * b.w;
  }
  ((float4*)out)[i] = v;
}

extern "C" void kernel_launch(void* const* d_in, const int* in_sizes, int n_in,
                              void* d_out, int out_size, void* d_ws, size_t ws_size,
                              hipStream_t stream)
{
  const float* x  = (const float*)d_in[0];
  const float* W1 = (const float*)d_in[1];
  const float* b1 = (const float*)d_in[2];
  const float* W2 = (const float*)d_in[3];
  const float* b2 = (const float*)d_in[4];
  const float* Wg = (const float*)d_in[5];
  const float* bg = (const float*)d_in[6];
  float* out = (float*)d_out;

  // workspace layout
  char* ws = (char*)d_ws;
  float*          probs = (float*)ws;                                   // 128 KB
  unsigned short* xb    = (unsigned short*)(ws + (1u << 17));           // 8 MB
  unsigned short* W1t   = (unsigned short*)(ws + (1u << 17) + (8u << 20));       // 64 MB
  unsigned short* W2t   = (unsigned short*)(ws + (1u << 17) + (8u << 20) + (64u << 20)); // 64 MB
  unsigned short* hp    = (unsigned short*)(ws + (1u << 17) + (8u << 20) + (128u << 20)); // 256 MB
  // split-K partials alias W1t (dead after GEMM1): 4 x 16 MB fp32 = 64 MB
  float* partial = (float*)W1t;

  gating_kernel<<<B_DIM / 4, 256, 0, stream>>>(x, Wg, bg, probs);
  convert_x_kernel<<<(B_DIM * D_DIM / 4) / 256, 256, 0, stream>>>(x, xb);
  transpose_w1<<<dim3(H_DIM / 32, D_DIM / 32, E_DIM), 256, 0, stream>>>(W1, W1t);
  transpose_w2<<<dim3(O_DIM / 32, H_DIM / 32, E_DIM), 256, 0, stream>>>(W2, W2t);

  // GEMM1: h' = bf16(p * relu(x @ W1 + b1))   M=4096 N=32768 K=1024
  gemm8p<1><<<dim3((B_DIM / 256) * (KTOT / 256), 1), 512, 0, stream>>>(
      xb, W1t, hp, probs, b1, B_DIM, KTOT, D_DIM, D_DIM);

  // GEMM2: partial[ks] = h' @ W2 (chunk ks)    M=4096 N=1024 K=32768, split-K=4
  gemm8p<2><<<dim3((B_DIM / 256) * (O_DIM / 256), KSPLIT), 512, 0, stream>>>(
      hp, W2t, partial, probs, nullptr, B_DIM, O_DIM, KTOT, KTOT / KSPLIT);

  // reduce partials + sum_e p*b2 -> out
  reduce_out<<<(B_DIM * O_DIM / 4) / 256, 256, 0, stream>>>(partial, probs, b2, out);
}

// Round 6
// 980.356 us; speedup vs baseline: 1.5638x; 1.0812x over previous
//
#include <hip/hip_runtime.h>
#include <hip/hip_bf16.h>

// MoE forward, B=4096 E=8 D=1024 H=4096 O=1024, fp32 in/out, bf16 MFMA compute.
//
// out = sum_e p[b,e] * (relu(x @ W1[e] + b1[e]) @ W2[e] + b2[e])
//     = (h' @ W2flat) + sum_e p[b,e]*b2[e]      with h'[b, e*H+h] = p[b,e]*relu(...)
//
// GEMMs: 256x256 8-phase template, BK=64, 512 threads (8 waves 2Mx4N),
// 128KB LDS double-buffer, 3-bit row-XOR swizzle (o ^= ((o>>7)&7)<<4) applied to
// BOTH the global_load_lds source and the ds_read addrs (bank-balanced b128:
// 8 dwords/bank/wave = structural minimum), counted vmcnt(8), setprio on MFMA.

#define B_DIM 4096
#define E_DIM 8
#define D_DIM 1024
#define H_DIM 4096
#define O_DIM 1024
#define KTOT  (E_DIM * H_DIM)   // 32768
#define KSPLIT 4

typedef __attribute__((ext_vector_type(8))) short bf16x8;
typedef __attribute__((ext_vector_type(4))) float f32x4;

__device__ __forceinline__ unsigned short f2bf(float f) {
  union { float f; unsigned u; } c; c.f = f;
  unsigned r = c.u + 0x7fffu + ((c.u >> 16) & 1u);  // RNE
  return (unsigned short)(r >> 16);
}

__device__ __forceinline__ void gload_lds16(const void* g, void* l) {
  __builtin_amdgcn_global_load_lds(
      (const __attribute__((address_space(1))) void*)g,
      (__attribute__((address_space(3))) void*)l, 16, 0, 0);
}

__device__ __forceinline__ void barfence() {
  asm volatile("" ::: "memory");
  __builtin_amdgcn_s_barrier();
  asm volatile("" ::: "memory");
}

// 3-bit row-XOR swizzle: XOR 16B-slot bits (4-6) with row bits 0-2 (addr bits 7-9).
// Involution; row bits untouched. Quarter-wave (16 rows, fixed 16B col) spreads
// across all 8 slots of the 128B row -> 32 banks x 8 dwords = conflict-free b128.
__device__ __forceinline__ unsigned swzA(unsigned o) {
  return o ^ (((o >> 7) & 7u) << 4);
}

// Stage one 128x64 bf16 half-tile (16KB) into LDS segment `seg`.
// LDS dest linear (wave-uniform base + lane*16); global source pre-inverse-swizzled.
__device__ __forceinline__ void stageHalf(const char* gbase, size_t rowBytes, int kByte,
                                          char* seg, int tid) {
  #pragma unroll
  for (int r = 0; r < 2; ++r) {
    unsigned o = (unsigned)((r * 512 + tid) * 16);
    unsigned q = swzA(o);
    gload_lds16(gbase + (size_t)(q >> 7) * rowBytes + kByte + (q & 127), seg + o);
  }
}

// ---- one K-tile (BK=64) = 4 phases; quadrant order (0,0),(0,1),(1,1),(1,0) ----
template<bool STAGE, int VMN>
__device__ __forceinline__ void tile4(
    char* smem, int bufOff,
    const char* AbC, const char* BbC, size_t rbA, size_t rbB, int kStage,
    int wm, int wn, int lane, int tid, f32x4 (&acc)[8][4])
{
  bf16x8 aF[4][2], bLo[2][2], bHi[2][2];
  const char* aSeg = smem + bufOff + wm * 16384;            // A-half = wm
  const char* bSeg = smem + bufOff + (2 + (wn >> 1)) * 16384; // B-half = wn>>1

  // ---------- P1: quadrant (0,0) ----------
  #pragma unroll
  for (int m = 0; m < 4; ++m)
    #pragma unroll
    for (int kk = 0; kk < 2; ++kk) {
      unsigned o = (unsigned)((m * 16 + (lane & 15)) * 128 + kk * 64 + ((lane >> 4) * 16));
      aF[m][kk] = *(const bf16x8*)(aSeg + swzA(o));
    }
  #pragma unroll
  for (int n = 0; n < 2; ++n)
    #pragma unroll
    for (int kk = 0; kk < 2; ++kk) {
      unsigned o = (unsigned)(((wn & 1) * 64 + n * 16 + (lane & 15)) * 128 + kk * 64 + ((lane >> 4) * 16));
      bLo[n][kk] = *(const bf16x8*)(bSeg + swzA(o));
    }
  asm volatile("s_waitcnt lgkmcnt(8)" ::: "memory");
  barfence();
  asm volatile("s_waitcnt lgkmcnt(0)" ::: "memory");
  __builtin_amdgcn_s_setprio(1);
  #pragma unroll
  for (int m = 0; m < 4; ++m)
    #pragma unroll
    for (int n = 0; n < 2; ++n)
      #pragma unroll
      for (int kk = 0; kk < 2; ++kk)
        acc[m][n] = __builtin_amdgcn_mfma_f32_16x16x32_bf16(aF[m][kk], bLo[n][kk], acc[m][n], 0, 0, 0);
  __builtin_amdgcn_s_setprio(0);
  barfence();

  // ---------- P2: quadrant (0,1) ----------
  #pragma unroll
  for (int n = 0; n < 2; ++n)
    #pragma unroll
    for (int kk = 0; kk < 2; ++kk) {
      unsigned o = (unsigned)(((wn & 1) * 64 + (2 + n) * 16 + (lane & 15)) * 128 + kk * 64 + ((lane >> 4) * 16));
      bHi[n][kk] = *(const bf16x8*)(bSeg + swzA(o));
    }
  barfence();
  asm volatile("s_waitcnt lgkmcnt(0)" ::: "memory");
  __builtin_amdgcn_s_setprio(1);
  #pragma unroll
  for (int m = 0; m < 4; ++m)
    #pragma unroll
    for (int n = 0; n < 2; ++n)
      #pragma unroll
      for (int kk = 0; kk < 2; ++kk)
        acc[m][2 + n] = __builtin_amdgcn_mfma_f32_16x16x32_bf16(aF[m][kk], bHi[n][kk], acc[m][2 + n], 0, 0, 0);
  __builtin_amdgcn_s_setprio(0);
  barfence();

  // ---------- P3: quadrant (1,1); stage next-tile B halves ----------
  #pragma unroll
  for (int m = 0; m < 4; ++m)
    #pragma unroll
    for (int kk = 0; kk < 2; ++kk) {
      unsigned o = (unsigned)(((4 + m) * 16 + (lane & 15)) * 128 + kk * 64 + ((lane >> 4) * 16));
      aF[m][kk] = *(const bf16x8*)(aSeg + swzA(o));
    }
  if (STAGE) {
    stageHalf(BbC,                    rbB, kStage, smem + bufOff + 2 * 16384, tid);
    stageHalf(BbC + (size_t)128 * rbB, rbB, kStage, smem + bufOff + 3 * 16384, tid);
  }
  barfence();
  asm volatile("s_waitcnt lgkmcnt(0)" ::: "memory");
  __builtin_amdgcn_s_setprio(1);
  #pragma unroll
  for (int m = 0; m < 4; ++m)
    #pragma unroll
    for (int n = 0; n < 2; ++n)
      #pragma unroll
      for (int kk = 0; kk < 2; ++kk)
        acc[4 + m][2 + n] = __builtin_amdgcn_mfma_f32_16x16x32_bf16(aF[m][kk], bHi[n][kk], acc[4 + m][2 + n], 0, 0, 0);
  __builtin_amdgcn_s_setprio(0);
  barfence();

  // ---------- P4: quadrant (1,0); stage next-tile A halves; counted vmcnt ----------
  if (STAGE) {
    stageHalf(AbC,                    rbA, kStage, smem + bufOff + 0,     tid);
    stageHalf(AbC + (size_t)128 * rbA, rbA, kStage, smem + bufOff + 16384, tid);
  }
  if (VMN == 8)      asm volatile("s_waitcnt vmcnt(8)" ::: "memory");
  else if (VMN == 0) asm volatile("s_waitcnt vmcnt(0)" ::: "memory");
  barfence();
  __builtin_amdgcn_s_setprio(1);
  #pragma unroll
  for (int m = 0; m < 4; ++m)
    #pragma unroll
    for (int n = 0; n < 2; ++n)
      #pragma unroll
      for (int kk = 0; kk < 2; ++kk)
        acc[4 + m][n] = __builtin_amdgcn_mfma_f32_16x16x32_bf16(aF[m][kk], bLo[n][kk], acc[4 + m][n], 0, 0, 0);
  __builtin_amdgcn_s_setprio(0);
  barfence();
}

// ---------------- 256x256 8-phase GEMM  C = A[M,K] * Bt[N,K]^T ----------------
// MODE 1: Cout = bf16( relu(acc + b1[col]) * probs[row, col>>12] ), N=32768
// MODE 2: fp32 partial write to Cout + blockIdx.y*M*N (split-K), N=1024
template<int MODE>
__global__ __launch_bounds__(512, 2)
void gemm8p(const unsigned short* __restrict__ A,
            const unsigned short* __restrict__ Bt,
            void* __restrict__ Cout,
            const float* __restrict__ probs,
            const float* __restrict__ bias,
            int M, int N, int K, int kChunk)
{
  __shared__ __align__(16) char smem[131072];  // 2 buf x (A0,A1,B0,B1) x 16KB

  const int tid = threadIdx.x;
  const int wave = tid >> 6, lane = tid & 63;
  const int wm = wave >> 2, wn = wave & 3;

  int mt, nt, kBeg;
  if (MODE == 1) {
    // 2048 blocks; xcd = bid&7 (round-robin dispatch); per-XCD 256-block chunk
    // ordered as 4x4 (mt,nt) groups so resident panels ~ L2-sized.
    int bid = blockIdx.x;
    int xcd = bid & 7, seq = bid >> 3;
    int grp = seq >> 4, g = seq & 15;
    mt = (grp & 3) * 4 + (g & 3);
    nt = xcd * 16 + (grp >> 2) * 4 + (g >> 2);
    kBeg = 0;
  } else {
    // 64 x-blocks: the 4 nt-blocks sharing an A panel land on one XCD
    int x = blockIdx.x;
    mt = (x & 7) * 2 + ((x >> 3) & 1);
    nt = x >> 4;
    kBeg = blockIdx.y * kChunk;
  }

  const char* AbC = (const char*)(A + (size_t)mt * 256 * K);
  const char* BbC = (const char*)(Bt + (size_t)nt * 256 * K);
  const size_t rbA = (size_t)K * 2, rbB = (size_t)K * 2;

  f32x4 acc[8][4] = {};

  const int NT = kChunk / 64;   // K-tiles (even, >= 4)
  const int NI = NT / 2;

  // prologue: stage tile0 -> buf0, tile1 -> buf1 (order: B,B,A,A per tile)
  {
    int k0 = kBeg * 2, k1 = (kBeg + 64) * 2;
    stageHalf(BbC,                    rbB, k0, smem + 2 * 16384, tid);
    stageHalf(BbC + (size_t)128 * rbB, rbB, k0, smem + 3 * 16384, tid);
    stageHalf(AbC,                    rbA, k0, smem + 0,         tid);
    stageHalf(AbC + (size_t)128 * rbA, rbA, k0, smem + 16384,    tid);
    stageHalf(BbC,                    rbB, k1, smem + 65536 + 2 * 16384, tid);
    stageHalf(BbC + (size_t)128 * rbB, rbB, k1, smem + 65536 + 3 * 16384, tid);
    stageHalf(AbC,                    rbA, k1, smem + 65536 + 0,         tid);
    stageHalf(AbC + (size_t)128 * rbA, rbA, k1, smem + 65536 + 16384,    tid);
  }
  asm volatile("s_waitcnt vmcnt(8)" ::: "memory");  // tile0 landed
  barfence();

  for (int i = 0; i < NI - 1; ++i) {
    int ks0 = (kBeg + (2 * i + 2) * 64) * 2;
    int ks1 = (kBeg + (2 * i + 3) * 64) * 2;
    tile4<true, 8>(smem, 0,     AbC, BbC, rbA, rbB, ks0, wm, wn, lane, tid, acc);
    tile4<true, 8>(smem, 65536, AbC, BbC, rbA, rbB, ks1, wm, wn, lane, tid, acc);
  }
  // peeled last iteration: no staging; drain remaining loads before buf1 use
  tile4<false, 0>(smem, 0,     AbC, BbC, rbA, rbB, 0, wm, wn, lane, tid, acc);
  tile4<false, -1>(smem, 65536, AbC, BbC, rbA, rbB, 0, wm, wn, lane, tid, acc);

  // epilogue: C/D layout col = lane&15, row = (lane>>4)*4 + j  [m89-verified]
  const int colBase = nt * 256 + wn * 64;
  const int rowBase = mt * 256 + wm * 128;
  #pragma unroll
  for (int m = 0; m < 8; ++m) {
    #pragma unroll
    for (int n = 0; n < 4; ++n) {
      const int col = colBase + n * 16 + (lane & 15);
      #pragma unroll
      for (int j = 0; j < 4; ++j) {
        const int row = rowBase + m * 16 + ((lane >> 4) * 4) + j;
        float v = acc[m][n][j];
        if (MODE == 1) {
          v += bias[col];
          v = fmaxf(v, 0.0f) * probs[row * E_DIM + (col >> 12)];
          ((unsigned short*)Cout)[(size_t)row * N + col] = f2bf(v);
        } else {
          float* dst = (float*)Cout + (size_t)blockIdx.y * M * N;
          dst[(size_t)row * N + col] = v;
        }
      }
    }
  }
}

// ---------------- gating: probs[b,e] = softmax(x @ Wg + bg) ----------------
__global__ __launch_bounds__(256) void gating_kernel(
    const float* __restrict__ x, const float* __restrict__ Wg,
    const float* __restrict__ bg, float* __restrict__ probs)
{
  __shared__ float sWg[D_DIM * E_DIM];  // 32 KB
  for (int i = threadIdx.x; i < D_DIM * E_DIM; i += 256) sWg[i] = Wg[i];
  __syncthreads();

  const int wave = threadIdx.x >> 6, lane = threadIdx.x & 63;
  const int b = blockIdx.x * 4 + wave;

  float acc[E_DIM] = {};
  const float* xr = x + (size_t)b * D_DIM;
  #pragma unroll
  for (int i = 0; i < D_DIM / 64; ++i) {
    int d = i * 64 + lane;
    float xv = xr[d];
    #pragma unroll
    for (int e = 0; e < E_DIM; ++e) acc[e] += xv * sWg[d * E_DIM + e];
  }
  #pragma unroll
  for (int e = 0; e < E_DIM; ++e) {
    #pragma unroll
    for (int off = 32; off > 0; off >>= 1) acc[e] += __shfl_down(acc[e], off);
  }
  if (lane == 0) {
    float m = -1e30f;
    #pragma unroll
    for (int e = 0; e < E_DIM; ++e) { acc[e] += bg[e]; m = fmaxf(m, acc[e]); }
    float p[E_DIM]; float s = 0.f;
    #pragma unroll
    for (int e = 0; e < E_DIM; ++e) { p[e] = expf(acc[e] - m); s += p[e]; }
    float inv = 1.0f / s;
    #pragma unroll
    for (int e = 0; e < E_DIM; ++e) probs[(size_t)b * E_DIM + e] = p[e] * inv;
  }
}

// ---------------- x (fp32) -> xb (bf16), same layout ----------------
__global__ __launch_bounds__(256) void convert_x_kernel(
    const float* __restrict__ x, unsigned short* __restrict__ xb)
{
  int i = blockIdx.x * 256 + threadIdx.x;  // one float4 per thread
  const float4* src = (const float4*)x;
  float4 v = src[i];
  union { unsigned short u[4]; unsigned long long q; } o;
  o.u[0] = f2bf(v.x); o.u[1] = f2bf(v.y); o.u[2] = f2bf(v.z); o.u[3] = f2bf(v.w);
  *(unsigned long long*)(xb + (size_t)i * 4) = o.q;
}

// ---------------- W1 [E][D][H] fp32 -> W1t [(e*H+h)][D] bf16 ----------------
__global__ __launch_bounds__(256) void transpose_w1(
    const float* __restrict__ W1, unsigned short* __restrict__ W1t)
{
  __shared__ float t[32][33];
  const int e = blockIdx.z;
  const int d0 = blockIdx.y * 32;   // over D
  const int h0 = blockIdx.x * 32;   // over H
  const int tx = threadIdx.x & 31, ty = threadIdx.x >> 5;
  const float* src = W1 + (size_t)e * D_DIM * H_DIM;
  #pragma unroll
  for (int i = 0; i < 4; ++i)
    t[ty + 8 * i][tx] = src[(size_t)(d0 + ty + 8 * i) * H_DIM + h0 + tx];
  __syncthreads();
  #pragma unroll
  for (int i = 0; i < 4; ++i)
    W1t[((size_t)e * H_DIM + h0 + ty + 8 * i) * D_DIM + d0 + tx] =
        f2bf(t[tx][ty + 8 * i]);
}

// ---------------- W2 [E][H][O] fp32 -> W2t [O][E*H] bf16 ----------------
__global__ __launch_bounds__(256) void transpose_w2(
    const float* __restrict__ W2, unsigned short* __restrict__ W2t)
{
  __shared__ float t[32][33];
  const int e = blockIdx.z;
  const int h0 = blockIdx.y * 32;   // over H
  const int o0 = blockIdx.x * 32;   // over O
  const int tx = threadIdx.x & 31, ty = threadIdx.x >> 5;
  const float* src = W2 + (size_t)e * H_DIM * O_DIM;
  #pragma unroll
  for (int i = 0; i < 4; ++i)
    t[ty + 8 * i][tx] = src[(size_t)(h0 + ty + 8 * i) * O_DIM + o0 + tx];
  __syncthreads();
  #pragma unroll
  for (int i = 0; i < 4; ++i)
    W2t[(size_t)(o0 + ty + 8 * i) * KTOT + (size_t)e * H_DIM + h0 + tx] =
        f2bf(t[tx][ty + 8 * i]);
}

// ---------------- reduce split-K partials + bias correction ----------------
__global__ __launch_bounds__(256) void reduce_out(
    const float* __restrict__ partial, const float* __restrict__ probs,
    const float* __restrict__ b2, float* __restrict__ out)
{
  const int i = blockIdx.x * 256 + threadIdx.x;        // over B*O/4 float4s
  const int row = i >> 8;                              // O/4 = 256 float4 per row
  const int colv = i & 255;
  const size_t plane = (size_t)B_DIM * O_DIM / 4;

  float4 v = make_float4(0.f, 0.f, 0.f, 0.f);
  #pragma unroll
  for (int ks = 0; ks < KSPLIT; ++ks) {
    float4 p = ((const float4*)partial)[ks * plane + i];
    v.x += p.x; v.y += p.y; v.z += p.z; v.w += p.w;
  }
  #pragma unroll
  for (int e = 0; e < E_DIM; ++e) {
    float pe = probs[row * E_DIM + e];
    float4 b = ((const float4*)b2)[e * (O_DIM / 4) + colv];
    v.x += pe * b.x; v.y += pe * b.y; v.z += pe * b.z; v.w += pe * b.w;
  }
  ((float4*)out)[i] = v;
}

extern "C" void kernel_launch(void* const* d_in, const int* in_sizes, int n_in,
                              void* d_out, int out_size, void* d_ws, size_t ws_size,
                              hipStream_t stream)
{
  const float* x  = (const float*)d_in[0];
  const float* W1 = (const float*)d_in[1];
  const float* b1 = (const float*)d_in[2];
  const float* W2 = (const float*)d_in[3];
  const float* b2 = (const float*)d_in[4];
  const float* Wg = (const float*)d_in[5];
  const float* bg = (const float*)d_in[6];
  float* out = (float*)d_out;

  // workspace layout
  char* ws = (char*)d_ws;
  float*          probs = (float*)ws;                                   // 128 KB
  unsigned short* xb    = (unsigned short*)(ws + (1u << 17));           // 8 MB
  unsigned short* W1t   = (unsigned short*)(ws + (1u << 17) + (8u << 20));       // 64 MB
  unsigned short* W2t   = (unsigned short*)(ws + (1u << 17) + (8u << 20) + (64u << 20)); // 64 MB
  unsigned short* hp    = (unsigned short*)(ws + (1u << 17) + (8u << 20) + (128u << 20)); // 256 MB
  // split-K partials alias W1t (dead after GEMM1): 4 x 16 MB fp32 = 64 MB
  float* partial = (float*)W1t;

  gating_kernel<<<B_DIM / 4, 256, 0, stream>>>(x, Wg, bg, probs);
  convert_x_kernel<<<(B_DIM * D_DIM / 4) / 256, 256, 0, stream>>>(x, xb);
  transpose_w1<<<dim3(H_DIM / 32, D_DIM / 32, E_DIM), 256, 0, stream>>>(W1, W1t);
  transpose_w2<<<dim3(O_DIM / 32, H_DIM / 32, E_DIM), 256, 0, stream>>>(W2, W2t);

  // GEMM1: h' = bf16(p * relu(x @ W1 + b1))   M=4096 N=32768 K=1024
  gemm8p<1><<<dim3((B_DIM / 256) * (KTOT / 256), 1), 512, 0, stream>>>(
      xb, W1t, hp, probs, b1, B_DIM, KTOT, D_DIM, D_DIM);

  // GEMM2: partial[ks] = h' @ W2 (chunk ks)    M=4096 N=1024 K=32768, split-K=4
  gemm8p<2><<<dim3((B_DIM / 256) * (O_DIM / 256), KSPLIT), 512, 0, stream>>>(
      hp, W2t, partial, probs, nullptr, B_DIM, O_DIM, KTOT, KTOT / KSPLIT);

  // reduce partials + sum_e p*b2 -> out
  reduce_out<<<(B_DIM * O_DIM / 4) / 256, 256, 0, stream>>>(partial, probs, b2, out);
}